// Round 1
// baseline (241.842 us; speedup 1.0000x reference)
//
#include <hip/hip_runtime.h>
#include <math.h>

// x: (4, 8192, 1024) f32. _mod_step is an exact identity, so the whole problem
// reduces to: h = sigmoid(x·halt_w + halt_b) per token; 3-step ACT recurrence
// -> (P, n); out = P*x; ponder = 0.01*mean(n).
#define N_TOKENS 32768   // 4 * 8192
#define DIM      1024
#define WAVES_PER_BLOCK 4
#define TOK_PER_WAVE 8   // 8192/(4*8) = 1024 blocks -> 8x fewer atomics

typedef float v4f __attribute__((ext_vector_type(4)));

__global__ void modgpt_init(int* __restrict__ n_acc) {
    if (threadIdx.x == 0 && blockIdx.x == 0) n_acc[0] = 0;
}

__global__ __launch_bounds__(256) void modgpt_main(
        const float* __restrict__ x,
        const float* __restrict__ halt_w,
        const float* __restrict__ halt_b,
        float* __restrict__ out,
        int* __restrict__ n_acc) {
    const int wave = threadIdx.x >> 6;
    const int lane = threadIdx.x & 63;
    const int token0 = (blockIdx.x * WAVES_PER_BLOCK + wave) * TOK_PER_WAVE;

    const v4f* __restrict__ xin = (const v4f*)(x + (size_t)token0 * DIM);
    v4f* __restrict__ oout      = (v4f*)(out + (size_t)token0 * DIM);
    const v4f* __restrict__ w4  = (const v4f*)halt_w;

    // halt weights: resident in registers for all 8 tokens (L1-hot anyway)
    const v4f w0 = w4[lane];
    const v4f w1 = w4[lane + 64];
    const v4f w2 = w4[lane + 128];
    const v4f w3 = w4[lane + 192];
    const float hb = halt_b[0];

    int n_sum = 0;

    // software pipeline: token t's reduce chain overlaps token t+1's loads
    v4f c0 = xin[lane];
    v4f c1 = xin[lane + 64];
    v4f c2 = xin[lane + 128];
    v4f c3 = xin[lane + 192];

    #pragma unroll
    for (int t = 0; t < TOK_PER_WAVE; ++t) {
        v4f p0, p1, p2, p3;
        if (t + 1 < TOK_PER_WAVE) {
            const v4f* nx = xin + (size_t)(t + 1) * 256;
            p0 = nx[lane];
            p1 = nx[lane + 64];
            p2 = nx[lane + 128];
            p3 = nx[lane + 192];
        }

        // per-lane partial dot (16 elements), then wave-64 butterfly
        v4f m = c0 * w0 + c1 * w1 + c2 * w2 + c3 * w3;
        float dot = m.x + m.y + m.z + m.w;
        #pragma unroll
        for (int off = 32; off >= 1; off >>= 1)
            dot += __shfl_xor(dot, off, 64);

        const float h = 1.0f / (1.0f + expf(-(dot + hb)));

        // exact ACT recurrence (EPS = 0.01)
        float acc = 0.0f, rem = 1.0f, P = 0.0f;
        int n = 0;
        #pragma unroll
        for (int s = 0; s < 3; ++s) {
            if (acc < 0.99f) {
                const float na = acc + h;
                const float p  = (na > 0.99f) ? rem : h;
                P   += p;
                acc += p;
                rem -= p;
                n   += 1;
            }
        }
        n_sum += n;

        // nontemporal stores: out is write-once, keep x resident in L2/LLC
        v4f* op = oout + (size_t)t * 256;
        __builtin_nontemporal_store(c0 * P, op + lane);
        __builtin_nontemporal_store(c1 * P, op + lane + 64);
        __builtin_nontemporal_store(c2 * P, op + lane + 128);
        __builtin_nontemporal_store(c3 * P, op + lane + 192);

        c0 = p0; c1 = p1; c2 = p2; c3 = p3;
    }

    // per-block n reduction -> one atomic per block (1024 total)
    __shared__ int sn[WAVES_PER_BLOCK];
    if (lane == 0) sn[wave] = n_sum;
    __syncthreads();
    if (threadIdx.x == 0)
        atomicAdd(n_acc, sn[0] + sn[1] + sn[2] + sn[3]);
}

__global__ void modgpt_finalize(const int* __restrict__ n_acc,
                                float* __restrict__ ponder_out) {
    if (threadIdx.x == 0 && blockIdx.x == 0)
        ponder_out[0] = 0.01f * ((float)n_acc[0] / (float)N_TOKENS);
}

extern "C" void kernel_launch(void* const* d_in, const int* in_sizes, int n_in,
                              void* d_out, int out_size, void* d_ws, size_t ws_size,
                              hipStream_t stream) {
    const float* x        = (const float*)d_in[0];
    // d_in[1] = router_w : mathematically unused (mod step is identity)
    const float* halt_w   = (const float*)d_in[2];
    const float* halt_b   = (const float*)d_in[3];
    float* out            = (float*)d_out;
    int*   n_acc          = (int*)d_ws;

    modgpt_init<<<1, 64, 0, stream>>>(n_acc);
    modgpt_main<<<N_TOKENS / (WAVES_PER_BLOCK * TOK_PER_WAVE), 256, 0, stream>>>(
        x, halt_w, halt_b, out, n_acc);
    modgpt_finalize<<<1, 64, 0, stream>>>(n_acc, out + (size_t)N_TOKENS * DIM);
}

// Round 2
// 238.267 us; speedup vs baseline: 1.0150x; 1.0150x over previous
//
#include <hip/hip_runtime.h>
#include <math.h>

// x: (4, 8192, 1024) f32. _mod_step is an exact identity, so the whole problem
// reduces to: h = sigmoid(x·halt_w + halt_b) per token; 3-step ACT recurrence
// -> (P, n); out = P*x; ponder = 0.01*mean(n).
//
// R1: one token per wave (was 8), 8192 blocks (was 1024). Theory: main kernel
// was memory-LATENCY bound (2.55 TB/s @ 30% occupancy, 24k cycles/token) --
// fix with TLP, not ILP. n-atomics scattered over 64 cacheline-strided slots.
#define N_TOKENS 32768   // 4 * 8192
#define DIM      1024
#define N_SLOTS  64      // scattered n accumulators, 1 per 128B line
#define SLOT_STRIDE 32   // ints -> 128 B

typedef float v4f __attribute__((ext_vector_type(4)));

__global__ void modgpt_init(int* __restrict__ n_acc) {
    if (blockIdx.x == 0 && threadIdx.x < N_SLOTS)
        n_acc[threadIdx.x * SLOT_STRIDE] = 0;
}

__global__ __launch_bounds__(256) void modgpt_main(
        const float* __restrict__ x,
        const float* __restrict__ halt_w,
        const float* __restrict__ halt_b,
        float* __restrict__ out,
        int* __restrict__ n_acc) {
    const int wave = threadIdx.x >> 6;
    const int lane = threadIdx.x & 63;
    const int token = blockIdx.x * 4 + wave;

    const v4f* __restrict__ xin = (const v4f*)(x + (size_t)token * DIM);
    v4f* __restrict__ op        = (v4f*)(out + (size_t)token * DIM);
    const v4f* __restrict__ w4  = (const v4f*)halt_w;

    // issue the 4 HBM loads first; weight loads are L1/L2-hot
    const v4f c0 = xin[lane];
    const v4f c1 = xin[lane + 64];
    const v4f c2 = xin[lane + 128];
    const v4f c3 = xin[lane + 192];

    const v4f w0 = w4[lane];
    const v4f w1 = w4[lane + 64];
    const v4f w2 = w4[lane + 128];
    const v4f w3 = w4[lane + 192];
    const float hb = halt_b[0];

    // per-lane partial dot (16 elements), then wave-64 butterfly
    v4f m = c0 * w0 + c1 * w1 + c2 * w2 + c3 * w3;
    float dot = m.x + m.y + m.z + m.w;
    #pragma unroll
    for (int off = 32; off >= 1; off >>= 1)
        dot += __shfl_xor(dot, off, 64);

    const float h = 1.0f / (1.0f + expf(-(dot + hb)));

    // exact ACT recurrence (EPS = 0.01)
    float acc = 0.0f, rem = 1.0f, P = 0.0f;
    int n = 0;
    #pragma unroll
    for (int s = 0; s < 3; ++s) {
        if (acc < 0.99f) {
            const float na = acc + h;
            const float p  = (na > 0.99f) ? rem : h;
            P   += p;
            acc += p;
            rem -= p;
            n   += 1;
        }
    }

    // nontemporal stores: out is write-once; preserve x residency in LLC
    __builtin_nontemporal_store(c0 * P, op + lane);
    __builtin_nontemporal_store(c1 * P, op + lane + 64);
    __builtin_nontemporal_store(c2 * P, op + lane + 128);
    __builtin_nontemporal_store(c3 * P, op + lane + 192);

    // per-block n reduction -> one atomic per block, scattered over 64 lines
    __shared__ int sn[4];
    if (lane == 0) sn[wave] = n;
    __syncthreads();
    if (threadIdx.x == 0)
        atomicAdd(n_acc + (blockIdx.x & (N_SLOTS - 1)) * SLOT_STRIDE,
                  sn[0] + sn[1] + sn[2] + sn[3]);
}

__global__ void modgpt_finalize(const int* __restrict__ n_acc,
                                float* __restrict__ ponder_out) {
    int v = n_acc[(threadIdx.x & 63) * SLOT_STRIDE];
    #pragma unroll
    for (int off = 32; off >= 1; off >>= 1)
        v += __shfl_xor(v, off, 64);
    if (threadIdx.x == 0)
        ponder_out[0] = 0.01f * ((float)v / (float)N_TOKENS);
}

extern "C" void kernel_launch(void* const* d_in, const int* in_sizes, int n_in,
                              void* d_out, int out_size, void* d_ws, size_t ws_size,
                              hipStream_t stream) {
    const float* x        = (const float*)d_in[0];
    // d_in[1] = router_w : mathematically unused (mod step is identity)
    const float* halt_w   = (const float*)d_in[2];
    const float* halt_b   = (const float*)d_in[3];
    float* out            = (float*)d_out;
    int*   n_acc          = (int*)d_ws;

    modgpt_init<<<1, 64, 0, stream>>>(n_acc);
    modgpt_main<<<N_TOKENS / 4, 256, 0, stream>>>(x, halt_w, halt_b, out, n_acc);
    modgpt_finalize<<<1, 64, 0, stream>>>(n_acc, out + (size_t)N_TOKENS * DIM);
}

// Round 3
// 235.710 us; speedup vs baseline: 1.0260x; 1.0108x over previous
//
#include <hip/hip_runtime.h>
#include <math.h>

// x: (4, 8192, 1024) f32. _mod_step is an exact identity, so the whole problem
// reduces to: h = sigmoid(x·halt_w + halt_b) per token; 3-step ACT recurrence
// -> (P, n); out = P*x; ponder = 0.01*mean(n).
//
// R2: ONE variable changed vs R1 -- nontemporal stores -> plain stores.
// Theory: nt-stores bypass L2, giving HBM fine-grained read/write turnaround
// on every burst (structure-invariant 2.55 TB/s in R0 AND R1). Plain stores
// aggregate in L2 and drain in long same-direction runs (fill=6.7, copy=6.3).
#define N_TOKENS 32768   // 4 * 8192
#define DIM      1024
#define N_SLOTS  64      // scattered n accumulators, 1 per 128B line
#define SLOT_STRIDE 32   // ints -> 128 B

typedef float v4f __attribute__((ext_vector_type(4)));

__global__ void modgpt_init(int* __restrict__ n_acc) {
    if (blockIdx.x == 0 && threadIdx.x < N_SLOTS)
        n_acc[threadIdx.x * SLOT_STRIDE] = 0;
}

__global__ __launch_bounds__(256) void modgpt_main(
        const float* __restrict__ x,
        const float* __restrict__ halt_w,
        const float* __restrict__ halt_b,
        float* __restrict__ out,
        int* __restrict__ n_acc) {
    const int wave = threadIdx.x >> 6;
    const int lane = threadIdx.x & 63;
    const int token = blockIdx.x * 4 + wave;

    const v4f* __restrict__ xin = (const v4f*)(x + (size_t)token * DIM);
    v4f* __restrict__ op        = (v4f*)(out + (size_t)token * DIM);
    const v4f* __restrict__ w4  = (const v4f*)halt_w;

    // issue the 4 HBM loads first; weight loads are L1/L2-hot
    const v4f c0 = xin[lane];
    const v4f c1 = xin[lane + 64];
    const v4f c2 = xin[lane + 128];
    const v4f c3 = xin[lane + 192];

    const v4f w0 = w4[lane];
    const v4f w1 = w4[lane + 64];
    const v4f w2 = w4[lane + 128];
    const v4f w3 = w4[lane + 192];
    const float hb = halt_b[0];

    // per-lane partial dot (16 elements), then wave-64 butterfly
    v4f m = c0 * w0 + c1 * w1 + c2 * w2 + c3 * w3;
    float dot = m.x + m.y + m.z + m.w;
    #pragma unroll
    for (int off = 32; off >= 1; off >>= 1)
        dot += __shfl_xor(dot, off, 64);

    const float h = 1.0f / (1.0f + expf(-(dot + hb)));

    // exact ACT recurrence (EPS = 0.01)
    float acc = 0.0f, rem = 1.0f, P = 0.0f;
    int n = 0;
    #pragma unroll
    for (int s = 0; s < 3; ++s) {
        if (acc < 0.99f) {
            const float na = acc + h;
            const float p  = (na > 0.99f) ? rem : h;
            P   += p;
            acc += p;
            rem -= p;
            n   += 1;
        }
    }

    // PLAIN stores (the R2 change): let L2 aggregate the write stream so DRAM
    // sees long same-direction bursts instead of per-KB read/write turnaround.
    op[lane]       = c0 * P;
    op[lane + 64]  = c1 * P;
    op[lane + 128] = c2 * P;
    op[lane + 192] = c3 * P;

    // per-block n reduction -> one atomic per block, scattered over 64 lines
    __shared__ int sn[4];
    if (lane == 0) sn[wave] = n;
    __syncthreads();
    if (threadIdx.x == 0)
        atomicAdd(n_acc + (blockIdx.x & (N_SLOTS - 1)) * SLOT_STRIDE,
                  sn[0] + sn[1] + sn[2] + sn[3]);
}

__global__ void modgpt_finalize(const int* __restrict__ n_acc,
                                float* __restrict__ ponder_out) {
    int v = n_acc[(threadIdx.x & 63) * SLOT_STRIDE];
    #pragma unroll
    for (int off = 32; off >= 1; off >>= 1)
        v += __shfl_xor(v, off, 64);
    if (threadIdx.x == 0)
        ponder_out[0] = 0.01f * ((float)v / (float)N_TOKENS);
}

extern "C" void kernel_launch(void* const* d_in, const int* in_sizes, int n_in,
                              void* d_out, int out_size, void* d_ws, size_t ws_size,
                              hipStream_t stream) {
    const float* x        = (const float*)d_in[0];
    // d_in[1] = router_w : mathematically unused (mod step is identity)
    const float* halt_w   = (const float*)d_in[2];
    const float* halt_b   = (const float*)d_in[3];
    float* out            = (float*)d_out;
    int*   n_acc          = (int*)d_ws;

    modgpt_init<<<1, 64, 0, stream>>>(n_acc);
    modgpt_main<<<N_TOKENS / 4, 256, 0, stream>>>(x, halt_w, halt_b, out, n_acc);
    modgpt_finalize<<<1, 64, 0, stream>>>(n_acc, out + (size_t)N_TOKENS * DIM);
}